// Round 7
// baseline (219.226 us; speedup 1.0000x reference)
//
#include <hip/hip_runtime.h>
#include <hip/hip_bf16.h>

// out[bw][m][c] = sum_n posmap[m][n][c%4] * x[bw][n][c] + bias[m]
// pos_score depends only on d=n-m  =>  interior m (8..247) share ONE 17-tap
// stencil per s-group (68 scalars in SGPRs). 16 edge rows use per-m taps.
//
// R7 = R3's proven staging (global_load_lds, linear LDS, conflict-free
//      (vg,vg+16) split, chunk-fastest grid)  [110us, clean writes]
//    + R5's SGPR stencil (pm LDS reads eliminated: 108 -> 40 ds_read_b128)
//    + MCHUNK 128 / 512-thr blocks: halo halved, 2 blocks/CU (16 waves) so
//      staging of one block overlaps compute of the other.
//    - R5's XCD swizzle (bloated WRITE 262->454 MB) and R6's direct-global
//      reads (latency-bound, 2.9 TB/s) are both reverted.

#define N_TOK 256
#define C_CH  128
#define NV    32              // c/4 float4 columns
#define HW    8               // band half-width (exp(-0.475 d^2): |d|>8 < 3e-18)
#define TAPS  17
#define PMPAD 18              // padded taps per m in ws table
#define MCHUNK 128            // m rows per block
#define ROWS  (MCHUNK + 2*HW) // 144 staged x rows
#define XFL4  (ROWS * NV)     // 4608 float4 = 72 KB
#define BLK   512

typedef const __attribute__((address_space(1))) void gvoid_t;
typedef __attribute__((address_space(3))) void       lvoid_t;

// ---------------- kernel 1: banded posmap table (256 x 18 float4) -----------
// pmb[m][d] (d = n-m+8, 0..16; 17 zero). Invalid n -> 0 weight. Row 128 is the
// interior stencil.
__global__ void pm_build_kernel(const float* __restrict__ centers,
                                const float* __restrict__ spreads,
                                float* __restrict__ pmb) {
    const int m    = blockIdx.x;       // 0..255
    const int lane = threadIdx.x;      // 0..63
    const int n    = m + lane - HW;
    const bool valid = (lane < TAPS) && ((unsigned)n < N_TOK);
    const float dd = (float)(lane - HW);

    float e[4];
#pragma unroll
    for (int s = 0; s < 4; ++s) {
        const float ctr = centers[s];
        const float spr = spreads[s];
        const float sc = (ctr * spr) * dd - 0.5f * spr * dd * dd;
        e[s] = valid ? expf(sc) : 0.0f;
    }
#pragma unroll
    for (int s = 0; s < 4; ++s) {
        float v = e[s];
#pragma unroll
        for (int off = 32; off; off >>= 1) v += __shfl_xor(v, off, 64);
        e[s] = e[s] / __shfl(v, 0, 64);   // 0 for invalid lanes
    }
    if (lane < PMPAD) {
        reinterpret_cast<float4*>(pmb)[m * PMPAD + lane] =
            make_float4(e[0], e[1], e[2], e[3]);
    }
}

// ---------------- kernel 2: SGPR-stencil banded contraction -----------------
// grid: dim3(2 chunks, 2048 bw) chunk-fastest. block: 512 thr = 32 mslots x
// 16 vgroups; thread: 4 m x cols {vg, vg+16}.
__global__ __launch_bounds__(BLK, 4)
void pm_apply_kernel(const float* __restrict__ x,
                     const float* __restrict__ pmb,
                     const float* __restrict__ bias,
                     float* __restrict__ out) {
    const int m0   = blockIdx.x * MCHUNK;   // 0 or 128
    const int bw   = blockIdx.y;            // 0..2047
    const int row0 = m0 - HW;
    const int tid  = threadIdx.x;

    __shared__ float4 lds_x[XFL4];          // 72 KB, linear [row][v]

    const float* xb = x + (size_t)bw * (N_TOK * C_CH);

    // stage x: 4608 float4 via global_load_lds (linear dest, clamped source)
#pragma unroll
    for (int i = 0; i < XFL4 / BLK; ++i) {  // 9
        const int idx = tid + i * BLK;
        const int r = idx >> 5;
        const int v = idx & 31;
        int n = row0 + r;
        n = n < 0 ? 0 : (n > N_TOK - 1 ? N_TOK - 1 : n);  // weight=0 there
        __builtin_amdgcn_global_load_lds((gvoid_t*)(xb + n * C_CH + v * 4),
                                         (lvoid_t*)&lds_x[idx], 16, 0, 0);
    }

    // interior stencil (pmb row 128) -> SGPRs (issued before the barrier so
    // the smem latency hides under the staging drain)
    float wsc[TAPS * 4];
    {
        const float* wrow = pmb + 128 * (PMPAD * 4);
#pragma unroll
        for (int t = 0; t < TAPS * 4; ++t)
            wsc[t] = __int_as_float(
                __builtin_amdgcn_readfirstlane(__float_as_int(wrow[t])));
    }

    __syncthreads();

    const int vg    = tid & 15;
    const int mslot = tid >> 4;             // 0..31
    const int mloc  = mslot * 4;
    const int mbase = m0 + mloc;

    float4 acc[4][2];
#pragma unroll
    for (int mi = 0; mi < 4; ++mi) {
        const float bv = bias[mbase + mi];
        acc[mi][0] = make_float4(bv, bv, bv, bv);
        acc[mi][1] = acc[mi][0];
    }

    const bool edge = (m0 == 0 && mslot < 2) || (m0 == MCHUNK && mslot >= 30);
    if (!edge) {
        // rows mloc..mloc+19 cover the 17-tap band of all 4 m
#pragma unroll
        for (int nr = 0; nr < 20; ++nr) {
            const int rbase = (mloc + nr) * NV;
            const float4 x0 = lds_x[rbase + vg];
            const float4 x1 = lds_x[rbase + vg + 16];
#pragma unroll
            for (int mi = 0; mi < 4; ++mi) {
                const int d = nr - mi;
                if (d >= 0 && d < TAPS) {   // compile-time per (nr,mi)
                    acc[mi][0].x += wsc[d * 4 + 0] * x0.x;
                    acc[mi][0].y += wsc[d * 4 + 1] * x0.y;
                    acc[mi][0].z += wsc[d * 4 + 2] * x0.z;
                    acc[mi][0].w += wsc[d * 4 + 3] * x0.w;
                    acc[mi][1].x += wsc[d * 4 + 0] * x1.x;
                    acc[mi][1].y += wsc[d * 4 + 1] * x1.y;
                    acc[mi][1].z += wsc[d * 4 + 2] * x1.z;
                    acc[mi][1].w += wsc[d * 4 + 3] * x1.w;
                }
            }
        }
    } else {
        // 16 edge rows total: per-m renormalized taps from pmb (L2, broadcast)
#pragma unroll
        for (int mi = 0; mi < 4; ++mi) {
            const float4* pmrow =
                reinterpret_cast<const float4*>(pmb) + (mbase + mi) * PMPAD;
#pragma unroll
            for (int t = 0; t < TAPS; ++t) {
                const float4 w = pmrow[t];
                const int rbase = (mloc + mi + t) * NV;
                const float4 x0 = lds_x[rbase + vg];
                const float4 x1 = lds_x[rbase + vg + 16];
                acc[mi][0].x += w.x * x0.x;
                acc[mi][0].y += w.y * x0.y;
                acc[mi][0].z += w.z * x0.z;
                acc[mi][0].w += w.w * x0.w;
                acc[mi][1].x += w.x * x1.x;
                acc[mi][1].y += w.y * x1.y;
                acc[mi][1].z += w.z * x1.z;
                acc[mi][1].w += w.w * x1.w;
            }
        }
    }

    float4* ob = reinterpret_cast<float4*>(out + (size_t)bw * (N_TOK * C_CH));
#pragma unroll
    for (int mi = 0; mi < 4; ++mi) {
        ob[(mbase + mi) * NV + vg] = acc[mi][0];
        ob[(mbase + mi) * NV + vg + 16] = acc[mi][1];
    }
}

extern "C" void kernel_launch(void* const* d_in, const int* in_sizes, int n_in,
                              void* d_out, int out_size, void* d_ws, size_t ws_size,
                              hipStream_t stream) {
    const float* x       = (const float*)d_in[0];  // (16,128,256,128)
    const float* centers = (const float*)d_in[1];  // (4,1)
    const float* spreads = (const float*)d_in[2];  // (4,1)
    const float* bias    = (const float*)d_in[3];  // (1,256,1)
    float* out = (float*)d_out;
    float* pmb = (float*)d_ws;                     // 256*18 float4 = 73.7 KB

    pm_build_kernel<<<dim3(N_TOK), dim3(64), 0, stream>>>(centers, spreads, pmb);

    const int n_bw = 16 * 128;                     // 2048
    pm_apply_kernel<<<dim3(N_TOK / MCHUNK, n_bw), dim3(BLK), 0, stream>>>(
        x, pmb, bias, out);
}

// Round 8
// 132.434 us; speedup vs baseline: 1.6554x; 1.6554x over previous
//
#include <hip/hip_runtime.h>
#include <hip/hip_bf16.h>

// out[bw][m][c] = sum_n posmap[m][n][c%4] * x[bw][n][c] + bias[m]
// pos_score depends only on d=n-m  =>  interior m (8..247) share ONE 17-tap
// stencil per s-group. 16 edge rows use renormalized per-m taps.
//
// R8 post-mortem-driven rebuild:
//  - R5/R7 WRITE bloat (416-454 MB vs 262 logical) was scratch spill: the
//    68-scalar readfirstlane stencil + LB(..,4) VGPR cap 64. Out sectors are
//    written exactly once, so extra HBM writes == spill traffic.
//  - Fix: stencil as 17 float4 in VGPRs (no readfirstlane, no SGPR cliff),
//    LB(256,2) (cap 256), R3's proven block/write geometry, x-only LDS (40KB).
//  - Per-thread LDS ops: 108 (R3) -> 40 ds_read_b128.

#define N_TOK 256
#define C_CH  128
#define NV    32              // c/4 float4 columns
#define HW    8               // band half-width (exp(-0.475 d^2): |d|>8 < 3e-18)
#define TAPS  17
#define PMPAD 18              // padded taps per m in ws table
#define MCHUNK 64             // m rows per block
#define ROWS  (MCHUNK + 2*HW) // 80 staged x rows
#define XFL4  (ROWS * NV)     // 2560 float4 = 40 KB

typedef const __attribute__((address_space(1))) void gvoid_t;
typedef __attribute__((address_space(3))) void       lvoid_t;

// ---------------- kernel 1: banded posmap table (256 x 18 float4) -----------
// pmb[m][d] (d = n-m+8, 0..16; 17 zero). Invalid n -> 0 weight. Row 128 is the
// interior stencil.
__global__ void pm_build_kernel(const float* __restrict__ centers,
                                const float* __restrict__ spreads,
                                float* __restrict__ pmb) {
    const int m    = blockIdx.x;       // 0..255
    const int lane = threadIdx.x;      // 0..63
    const int n    = m + lane - HW;
    const bool valid = (lane < TAPS) && ((unsigned)n < N_TOK);
    const float dd = (float)(lane - HW);

    float e[4];
#pragma unroll
    for (int s = 0; s < 4; ++s) {
        const float ctr = centers[s];
        const float spr = spreads[s];
        const float sc = (ctr * spr) * dd - 0.5f * spr * dd * dd;
        e[s] = valid ? expf(sc) : 0.0f;
    }
#pragma unroll
    for (int s = 0; s < 4; ++s) {
        float v = e[s];
#pragma unroll
        for (int off = 32; off; off >>= 1) v += __shfl_xor(v, off, 64);
        e[s] = e[s] / __shfl(v, 0, 64);   // 0 for invalid lanes
    }
    if (lane < PMPAD) {
        reinterpret_cast<float4*>(pmb)[m * PMPAD + lane] =
            make_float4(e[0], e[1], e[2], e[3]);
    }
}

// ---------------- kernel 2: VGPR-stencil banded contraction -----------------
// grid: dim3(4 chunks, 2048 bw) chunk-fastest (R3's proven order).
// block: 256 thr = 16 mslots x 16 vgroups; thread: 4 m x cols {vg, vg+16}.
__global__ __launch_bounds__(256, 2)
void pm_apply_kernel(const float* __restrict__ x,
                     const float* __restrict__ pmb,
                     const float* __restrict__ bias,
                     float* __restrict__ out) {
    const int m0   = blockIdx.x * MCHUNK;   // 0,64,128,192
    const int bw   = blockIdx.y;            // 0..2047
    const int row0 = m0 - HW;
    const int tid  = threadIdx.x;

    __shared__ float4 lds_x[XFL4];          // 40 KB, linear [row][v]

    const float* xb = x + (size_t)bw * (N_TOK * C_CH);

    // stage x: 2560 float4 via global_load_lds (linear dest, clamped source)
#pragma unroll
    for (int i = 0; i < XFL4 / 256; ++i) {  // 10
        const int idx = tid + i * 256;
        const int r = idx >> 5;
        const int v = idx & 31;
        int n = row0 + r;
        n = n < 0 ? 0 : (n > N_TOK - 1 ? N_TOK - 1 : n);  // weight=0 there
        __builtin_amdgcn_global_load_lds((gvoid_t*)(xb + n * C_CH + v * 4),
                                         (lvoid_t*)&lds_x[idx], 16, 0, 0);
    }

    // interior stencil (pmb row 128) -> 17 float4 in VGPRs (issued before the
    // barrier so L2 latency hides under the staging drain). Compile-time
    // indices only -> stays in registers.
    const float4* __restrict__ pm4 = reinterpret_cast<const float4*>(pmb);
    float4 wv[TAPS];
#pragma unroll
    for (int t = 0; t < TAPS; ++t) wv[t] = pm4[128 * PMPAD + t];

    __syncthreads();

    const int vg    = tid & 15;
    const int mslot = tid >> 4;             // 0..15
    const int mloc  = mslot * 4;
    const int mbase = m0 + mloc;

    float4 acc[4][2];
#pragma unroll
    for (int mi = 0; mi < 4; ++mi) {
        const float bv = bias[mbase + mi];
        acc[mi][0] = make_float4(bv, bv, bv, bv);
        acc[mi][1] = acc[mi][0];
    }

    const bool edge = (m0 == 0 && mslot < 2) || (m0 == 192 && mslot >= 14);
    if (!edge) {
        // rows mloc..mloc+19 cover the 17-tap band of all 4 m
#pragma unroll
        for (int nr = 0; nr < 20; ++nr) {
            const int rbase = (mloc + nr) * NV;
            const float4 x0 = lds_x[rbase + vg];
            const float4 x1 = lds_x[rbase + vg + 16];
#pragma unroll
            for (int mi = 0; mi < 4; ++mi) {
                const int d = nr - mi;
                if (d >= 0 && d < TAPS) {   // compile-time per (nr,mi)
                    const float4 w = wv[d];
                    acc[mi][0].x += w.x * x0.x;
                    acc[mi][0].y += w.y * x0.y;
                    acc[mi][0].z += w.z * x0.z;
                    acc[mi][0].w += w.w * x0.w;
                    acc[mi][1].x += w.x * x1.x;
                    acc[mi][1].y += w.y * x1.y;
                    acc[mi][1].z += w.z * x1.z;
                    acc[mi][1].w += w.w * x1.w;
                }
            }
        }
    } else {
        // 16 edge rows total: per-m renormalized taps from pmb (L2, broadcast)
#pragma unroll
        for (int mi = 0; mi < 4; ++mi) {
            const float4* pmrow = pm4 + (mbase + mi) * PMPAD;
#pragma unroll
            for (int t = 0; t < TAPS; ++t) {
                const float4 w = pmrow[t];
                const int rbase = (mloc + mi + t) * NV;
                const float4 x0 = lds_x[rbase + vg];
                const float4 x1 = lds_x[rbase + vg + 16];
                acc[mi][0].x += w.x * x0.x;
                acc[mi][0].y += w.y * x0.y;
                acc[mi][0].z += w.z * x0.z;
                acc[mi][0].w += w.w * x0.w;
                acc[mi][1].x += w.x * x1.x;
                acc[mi][1].y += w.y * x1.y;
                acc[mi][1].z += w.z * x1.z;
                acc[mi][1].w += w.w * x1.w;
            }
        }
    }

    float4* ob = reinterpret_cast<float4*>(out + (size_t)bw * (N_TOK * C_CH));
#pragma unroll
    for (int mi = 0; mi < 4; ++mi) {
        ob[(mbase + mi) * NV + vg] = acc[mi][0];
        ob[(mbase + mi) * NV + vg + 16] = acc[mi][1];
    }
}

extern "C" void kernel_launch(void* const* d_in, const int* in_sizes, int n_in,
                              void* d_out, int out_size, void* d_ws, size_t ws_size,
                              hipStream_t stream) {
    const float* x       = (const float*)d_in[0];  // (16,128,256,128)
    const float* centers = (const float*)d_in[1];  // (4,1)
    const float* spreads = (const float*)d_in[2];  // (4,1)
    const float* bias    = (const float*)d_in[3];  // (1,256,1)
    float* out = (float*)d_out;
    float* pmb = (float*)d_ws;                     // 256*18 float4 = 73.7 KB

    pm_build_kernel<<<dim3(N_TOK), dim3(64), 0, stream>>>(centers, spreads, pmb);

    const int n_bw = 16 * 128;                     // 2048
    pm_apply_kernel<<<dim3(N_TOK / MCHUNK, n_bw), dim3(256), 0, stream>>>(
        x, pmb, bias, out);
}